// Round 3
// baseline (351.825 us; speedup 1.0000x reference)
//
#include <hip/hip_runtime.h>
#include <cstdint>
#include <cstddef>

#define M_DIM 4096
#define K_DIM 4096
#define N_DIM 11008
#define BM 128
#define BN 256
#define BKI 64                          /* K bytes per tile */
#define NT (K_DIM / BKI)                /* 64 K-tiles */
#define NTM (M_DIM / BM)                /* 32 */
#define NTN (N_DIM / BN)                /* 43 */
#define TILE_A_BYTES (BM * BKI)         /* 8192  = 8 frags  */
#define TILE_B_BYTES (BN * BKI)         /* 16384 = 16 frags */
#define RING_STRIDE (TILE_A_BYTES + TILE_B_BYTES)  /* 24576 */
#define RING 3                          /* 72 KB LDS -> 2 blocks/CU */

typedef int   int4v   __attribute__((ext_vector_type(4)));
typedef float float4v __attribute__((ext_vector_type(4)));

__device__ __forceinline__ void gload_lds16(const void* g, void* l) {
  __builtin_amdgcn_global_load_lds(
      (const __attribute__((address_space(1))) unsigned int*)g,
      (__attribute__((address_space(3))) unsigned int*)l, 16, 0, 0);
}

// ---------------- x quantization: fp32 -> int8 ----------------
__global__ void quant_x_kernel(const float* __restrict__ x,
                               const float* __restrict__ scale_p,
                               const int* __restrict__ off_p,
                               signed char* __restrict__ xq, int total16) {
  const float inv = 1.0f / scale_p[0];
  const float off = (float)off_p[0];
  int tid = blockIdx.x * blockDim.x + threadIdx.x;
  int stride = gridDim.x * blockDim.x;
  const float4v* x4 = (const float4v*)x;
  int4v* out4 = (int4v*)xq;
  for (int i = tid; i < total16; i += stride) {
    int4v o;
#pragma unroll
    for (int j = 0; j < 4; ++j) {
      float4v v = x4[(size_t)i * 4 + j];
      int r = 0;
#pragma unroll
      for (int e = 0; e < 4; ++e) {
        float q = rintf(v[e] * inv) + off;     // round-half-even, matches jnp.round
        q = fminf(fmaxf(q, -128.0f), 127.0f);
        int qi = (int)q;
        r |= (qi & 0xff) << (8 * e);
      }
      o[j] = r;
    }
    out4[i] = o;
  }
}

// ---------------- weight pack: int32 carrier -> int8 ----------------
__global__ void pack_w_kernel(const int* __restrict__ w,
                              signed char* __restrict__ wq, int total16) {
  int tid = blockIdx.x * blockDim.x + threadIdx.x;
  int stride = gridDim.x * blockDim.x;
  const int4v* w4 = (const int4v*)w;
  int4v* out4 = (int4v*)wq;
  for (int i = tid; i < total16; i += stride) {
    int4v o;
#pragma unroll
    for (int j = 0; j < 4; ++j) {
      int4v v = w4[(size_t)i * 4 + j];
      o[j] = (v[0] & 0xff) | ((v[1] & 0xff) << 8) |
             ((v[2] & 0xff) << 16) | ((v[3] & 0xff) << 24);
    }
    out4[i] = o;
  }
}

// ---------------- int8 GEMM, 128x256 tile, 8 waves, 3-ring, 2 blocks/CU ----------
// A: xq [M][K] int8, B: wq [N][K] int8 (B^T), out fp32 [M][N]
// LDS fragment-packed: tile = 8 A-frags + 16 B-frags of 1 KB.  Fragment f holds
// rows 16f..16f+15 of the K-slice; lane l's 16B at f*1024 + l*16 is
// [16f + (l&15)][(l>>4)*16 ..+16] -> every ds_read_b128 is base + lane*16
// (contiguous, conflict-free; verified 0 conflicts in round 2).
__global__ __launch_bounds__(512, 4) void gemm_i8_kernel(
    const signed char* __restrict__ A,
    const signed char* __restrict__ B,
    const int* __restrict__ qbias,
    const float* __restrict__ dscale,
    float* __restrict__ out) {
  __shared__ __attribute__((aligned(16))) signed char lds[RING * RING_STRIDE];

  const int tid  = threadIdx.x;
  const int lane = tid & 63;
  const int wv   = tid >> 6;   // 0..7
  const int wr   = wv >> 2;    // 0..1  (M half, 64 rows each)
  const int wc   = wv & 3;     // 0..3  (N quarter, 64 cols each)

  // XCD swizzle: 1376 blocks, 172/XCD; within XCD tm varies fastest so 32
  // consecutive blocks share one B-panel (1 MB, L2-resident).
  int bid = blockIdx.x;
  int swz = (bid & 7) * ((NTM * NTN) >> 3) + (bid >> 3);
  int tm = swz & (NTM - 1);    // NTM = 32
  int tn = swz >> 5;           // 0..42

  // Staging: wave wv owns fragments f = 3*wv + i, i = 0..2 (24 frags total).
  // f < 8 -> A fragment f ; f >= 8 -> B fragment f-8.  LDS dst = f*1024.
  const signed char* gp[3];
  int lo[3];
#pragma unroll
  for (int i = 0; i < 3; ++i) {
    int f = wv * 3 + i;
    lo[i] = f * 1024;
    if (f < 8)
      gp[i] = A + (size_t)(tm * BM + f * 16 + (lane & 15)) * K_DIM + (lane >> 4) * 16;
    else
      gp[i] = B + (size_t)(tn * BN + (f - 8) * 16 + (lane & 15)) * K_DIM + (lane >> 4) * 16;
  }

#define STAGE(kt, roff) do { \
    gload_lds16(gp[0] + (size_t)(kt) * BKI, lds + (roff) + lo[0]); \
    gload_lds16(gp[1] + (size_t)(kt) * BKI, lds + (roff) + lo[1]); \
    gload_lds16(gp[2] + (size_t)(kt) * BKI, lds + (roff) + lo[2]); } while (0)

  // ds_read offsets: A frags wr*4 + mi, B frags wc*4 + ni
  const int rdA = (wr * 4) * 1024 + lane * 16;
  const int rdB = TILE_A_BYTES + (wc * 4) * 1024 + lane * 16;

  int4v acc[4][4];
#pragma unroll
  for (int i = 0; i < 4; ++i)
#pragma unroll
    for (int j = 0; j < 4; ++j) acc[i][j] = (int4v){0, 0, 0, 0};

  // ---- prologue: stage tiles 0,1; wait tile 0 landed (tile 1 in flight) ----
  STAGE(0, 0);
  STAGE(1, RING_STRIDE);
  asm volatile("s_waitcnt vmcnt(3)" ::: "memory");
  __builtin_amdgcn_s_barrier();

  int roff = 0;
  for (int kt = 0; kt < NT; ++kt) {
    int nxt = roff + 2 * RING_STRIDE;
    if (nxt >= RING * RING_STRIDE) nxt -= RING * RING_STRIDE;

    int4v afr[4], bfr[4];
#pragma unroll
    for (int mi = 0; mi < 4; ++mi)
      afr[mi] = *(const int4v*)(lds + roff + rdA + mi * 1024);
#pragma unroll
    for (int ni = 0; ni < 4; ++ni)
      bfr[ni] = *(const int4v*)(lds + roff + rdB + ni * 1024);

    if (kt + 2 < NT) STAGE(kt + 2, nxt);   // slot (kt+2)%3: reads of kt-1 done

    __builtin_amdgcn_s_setprio(1);
#pragma unroll
    for (int mi = 0; mi < 4; ++mi)
#pragma unroll
      for (int ni = 0; ni < 4; ++ni)
        acc[mi][ni] = __builtin_amdgcn_mfma_i32_16x16x64_i8(
            afr[mi], bfr[ni], acc[mi][ni], 0, 0, 0);
    __builtin_amdgcn_s_setprio(0);

    // counted wait: tile kt+1 landed; tile kt+2's 3 loads may stay in flight
    if (kt + 2 < NT) {
      asm volatile("s_waitcnt vmcnt(3)" ::: "memory");
      __builtin_amdgcn_s_barrier();
    } else if (kt + 1 < NT) {
      asm volatile("s_waitcnt vmcnt(0)" ::: "memory");
      __builtin_amdgcn_s_barrier();
    }
    roff += RING_STRIDE;
    if (roff >= RING * RING_STRIDE) roff -= RING * RING_STRIDE;
  }
#undef STAGE

  // ---- epilogue: out[m][n] = (acc + qbias[n]) * dscale[n] ----
  const int col = lane & 15;
  const int rb  = (lane >> 4) * 4;
  const int gm0 = tm * BM + wr * 64;
  const int gn0 = tn * BN + wc * 64;
#pragma unroll
  for (int ni = 0; ni < 4; ++ni) {
    int gn = gn0 + ni * 16 + col;
    float ds = dscale[gn];
    int qb = qbias[gn];
#pragma unroll
    for (int mi = 0; mi < 4; ++mi) {
      int gm = gm0 + mi * 16 + rb;
#pragma unroll
      for (int j = 0; j < 4; ++j)
        out[(size_t)(gm + j) * N_DIM + gn] = (float)(acc[mi][ni][j] + qb) * ds;
    }
  }
}

extern "C" void kernel_launch(void* const* d_in, const int* in_sizes, int n_in,
                              void* d_out, int out_size, void* d_ws, size_t ws_size,
                              hipStream_t stream) {
  const float* x      = (const float*)d_in[0];
  const int*   w      = (const int*)d_in[1];
  const float* dscale = (const float*)d_in[2];
  const float* iscale = (const float*)d_in[3];
  const int*   ioff   = (const int*)d_in[4];
  const int*   qbias  = (const int*)d_in[5];
  float* out = (float*)d_out;

  const size_t xq_bytes = (size_t)M_DIM * K_DIM;        // 16 MB
  const size_t wq_bytes = (size_t)N_DIM * K_DIM;        // 45 MB
  if (ws_size < xq_bytes + wq_bytes) return;

  signed char* xq = (signed char*)d_ws;
  signed char* wq = (signed char*)d_ws + xq_bytes;

  quant_x_kernel<<<2048, 256, 0, stream>>>(x, iscale, ioff, xq, M_DIM * K_DIM / 16);
  pack_w_kernel<<<2048, 256, 0, stream>>>(w, wq, N_DIM * K_DIM / 16);
  gemm_i8_kernel<<<NTM * NTN, 512, 0, stream>>>(xq, wq, qbias, dscale, out);
}

// Round 4
// 286.954 us; speedup vs baseline: 1.2261x; 1.2261x over previous
//
#include <hip/hip_runtime.h>
#include <cstdint>
#include <cstddef>

#define M_DIM 4096
#define K_DIM 4096
#define N_DIM 11008
#define BM 256
#define BN 256
#define BKB 128                       /* K bytes per K-tile (2 MFMA k-slices) */
#define NT (K_DIM / BKB)              /* 32 K-tiles */
#define NITER (NT / 2)                /* 16 iterations, 2 K-tiles each */
#define NTM (M_DIM / BM)              /* 16 */
#define NTN (N_DIM / BN)              /* 43 */
#define SLOT_BYTES 65536              /* per K-tile: A 32KB + B 32KB */
#define B_OFF 32768

typedef int   int4v   __attribute__((ext_vector_type(4)));
typedef float float4v __attribute__((ext_vector_type(4)));

__device__ __forceinline__ void gload_lds16(const void* g, void* l) {
  __builtin_amdgcn_global_load_lds(
      (const __attribute__((address_space(1))) unsigned int*)g,
      (__attribute__((address_space(3))) unsigned int*)l, 16, 0, 0);
}

// ---------------- x quantization: fp32 -> int8 ----------------
__global__ void quant_x_kernel(const float* __restrict__ x,
                               const float* __restrict__ scale_p,
                               const int* __restrict__ off_p,
                               signed char* __restrict__ xq, int total16) {
  const float inv = 1.0f / scale_p[0];
  const float off = (float)off_p[0];
  int tid = blockIdx.x * blockDim.x + threadIdx.x;
  int stride = gridDim.x * blockDim.x;
  const float4v* x4 = (const float4v*)x;
  int4v* out4 = (int4v*)xq;
  for (int i = tid; i < total16; i += stride) {
    int4v o;
#pragma unroll
    for (int j = 0; j < 4; ++j) {
      float4v v = x4[(size_t)i * 4 + j];
      int r = 0;
#pragma unroll
      for (int e = 0; e < 4; ++e) {
        float q = rintf(v[e] * inv) + off;     // round-half-even, matches jnp.round
        q = fminf(fmaxf(q, -128.0f), 127.0f);
        int qi = (int)q;
        r |= (qi & 0xff) << (8 * e);
      }
      o[j] = r;
    }
    out4[i] = o;
  }
}

// ---------------- weight pack: int32 carrier -> int8 ----------------
__global__ void pack_w_kernel(const int* __restrict__ w,
                              signed char* __restrict__ wq, int total16) {
  int tid = blockIdx.x * blockDim.x + threadIdx.x;
  int stride = gridDim.x * blockDim.x;
  const int4v* w4 = (const int4v*)w;
  int4v* out4 = (int4v*)wq;
  for (int i = tid; i < total16; i += stride) {
    int4v o;
#pragma unroll
    for (int j = 0; j < 4; ++j) {
      int4v v = w4[(size_t)i * 4 + j];
      o[j] = (v[0] & 0xff) | ((v[1] & 0xff) << 8) |
             ((v[2] & 0xff) << 16) | ((v[3] & 0xff) << 24);
    }
    out4[i] = o;
  }
}

// -------- int8 GEMM: 256x256 tile, 8 waves, 8-phase schedule, counted vmcnt ------
// A: xq [M][K] int8, B: wq [N][K] int8 (B^T), out fp32 [M][N]
// LDS fragment-packed (0 bank conflicts, verified): fragment(rg,ks) = 1KB holding
// rows rg*16..+15, K bytes ks*64..+63 of the K-tile; lane l's 16B at
// frag*1024 + l*16 is [rg*16+(l&15)][ks*64+(l>>4)*16 ..+16].
// Slot s (s=K-tile&1) at s*64KB; A frags 0..31, B frags at +32KB.
// Chunk c (c=0..3) of an operand = frags rg in {2c,2c+1,8+2c,9+2c} x ks —
// exactly the rows whose last ds_read is in compute-phase c (A) / phase 0 (B).
// Schedule per iteration (tiles 2t slot0, 2t+1 slot1), stage 1 A-chunk + 1
// B-chunk per phase; vmcnt(6) only at phases 3 and 7 (8 loads of the tile
// about to be computed drain; 6 newest stay in flight).
__global__ __launch_bounds__(512, 2) void gemm_i8_kernel(
    const signed char* __restrict__ A,
    const signed char* __restrict__ B,
    const int* __restrict__ qbias,
    const float* __restrict__ dscale,
    float* __restrict__ out) {
  __shared__ __attribute__((aligned(16))) signed char lds[2 * SLOT_BYTES];  // 128 KB

  const int tid  = threadIdx.x;
  const int lane = tid & 63;
  const int wv   = tid >> 6;   // 0..7
  const int wr   = wv >> 2;    // 0..1  (M half: 128 rows)
  const int wc   = wv & 3;     // 0..3  (N quarter: 64 cols)

  // XCD swizzle: 688 blocks, 86/XCD; per XCD: 2 tm-rows x 43 tn, tn-fastest.
  int bid = blockIdx.x;
  int swz = (bid & 7) * 86 + (bid >> 3);
  int tm = swz / NTN;
  int tn = swz % NTN;

  // ---- staging assignment: wave wv stages frag (rg = 2c + ro, ks = sks) ----
  const int sks = wv & 1;
  const int r2  = wv >> 1;
  const int ro  = (r2 & 1) | ((r2 & 2) << 2);   // 0,1,8,9

  const signed char* pA = A + (size_t)(tm * BM + ro * 16 + (lane & 15)) * K_DIM
                            + sks * 64 + (lane >> 4) * 16;
  const signed char* pB = B + (size_t)(tn * BN + ro * 16 + (lane & 15)) * K_DIM
                            + sks * 64 + (lane >> 4) * 16;
  const int ldsA0 = (ro * 2 + sks) * 1024;          // + c*4096 + slot*64K
  const int ldsB0 = B_OFF + (ro * 2 + sks) * 1024;

#define STG(ktS, c) do {                                                      \
    int ktw_ = (ktS) & (NT - 1);                                              \
    int sl_  = (ktw_ & 1) * SLOT_BYTES;                                       \
    gload_lds16(pA + (size_t)(c) * 32 * K_DIM + (size_t)ktw_ * BKB,           \
                lds + sl_ + ldsA0 + (c) * 4096);                              \
    gload_lds16(pB + (size_t)(c) * 32 * K_DIM + (size_t)ktw_ * BKB,           \
                lds + sl_ + ldsB0 + (c) * 4096); } while (0)

  // ---- ds_read bases (fragment-packed: base + lane*16, conflict-free) ----
  const int rdA0 = (wr * 8) * 2048 + lane * 16;          // + (2P+d)*2048 + ks*1024
  const int rdB0 = B_OFF + (wc * 4) * 2048 + lane * 16;  // + ni*2048 + ks*1024

  int4v acc[8][4];
#pragma unroll
  for (int i = 0; i < 8; ++i)
#pragma unroll
    for (int j = 0; j < 4; ++j) acc[i][j] = (int4v){0, 0, 0, 0};

  int4v bfr[4][2], afr[2][2];

#define PHASE(S, P, KTS, CH) do {                                             \
    const int sb_ = (S) * SLOT_BYTES;                                         \
    if ((P) == 0) {                                                           \
      _Pragma("unroll") for (int ni = 0; ni < 4; ++ni)                        \
        _Pragma("unroll") for (int ks = 0; ks < 2; ++ks)                      \
          bfr[ni][ks] = *(const int4v*)(lds + sb_ + rdB0 + ni * 2048 + ks * 1024); \
    }                                                                         \
    _Pragma("unroll") for (int d = 0; d < 2; ++d)                             \
      _Pragma("unroll") for (int ks = 0; ks < 2; ++ks)                        \
        afr[d][ks] = *(const int4v*)(lds + sb_ + rdA0 + (2 * (P) + d) * 2048 + ks * 1024); \
    STG(KTS, CH);                                                             \
    __builtin_amdgcn_s_barrier();                                             \
    asm volatile("s_waitcnt lgkmcnt(0)" ::: "memory");                        \
    __builtin_amdgcn_s_setprio(1);                                            \
    _Pragma("unroll") for (int d = 0; d < 2; ++d)                             \
      _Pragma("unroll") for (int ni = 0; ni < 4; ++ni)                        \
        _Pragma("unroll") for (int ks = 0; ks < 2; ++ks)                      \
          acc[2 * (P) + d][ni] = __builtin_amdgcn_mfma_i32_16x16x64_i8(       \
              afr[d][ks], bfr[ni][ks], acc[2 * (P) + d][ni], 0, 0, 0);        \
    __builtin_amdgcn_s_setprio(0);                                            \
    if ((P) == 3) asm volatile("s_waitcnt vmcnt(6)" ::: "memory");            \
    __builtin_amdgcn_s_barrier();                                             \
  } while (0)

  // ---- prologue: tile0 fully (8 loads), tile1 chunks 0-2 (6 loads) ----
#pragma unroll
  for (int c = 0; c < 4; ++c) STG(0, c);
#pragma unroll
  for (int c = 0; c < 3; ++c) STG(1, c);
  asm volatile("s_waitcnt vmcnt(6)" ::: "memory");   // tile0 landed
  __builtin_amdgcn_s_barrier();

  for (int t = 0; t < NITER; ++t) {
    const int k0 = 2 * t;
    PHASE(0, 0, k0 + 1, 3);   // finish staging tile 2t+1
    PHASE(0, 1, k0 + 2, 0);   // begin staging tile 2t+2 (slot 0, freed regions)
    PHASE(0, 2, k0 + 2, 1);
    PHASE(0, 3, k0 + 2, 2);   // vmcnt(6): tile 2t+1 fully landed
    PHASE(1, 0, k0 + 2, 3);
    PHASE(1, 1, k0 + 3, 0);   // begin staging tile 2t+3 (slot 1)
    PHASE(1, 2, k0 + 3, 1);
    PHASE(1, 3, k0 + 3, 2);   // vmcnt(6): tile 2t+2 fully landed
  }
  asm volatile("s_waitcnt vmcnt(0)" ::: "memory");   // drain tail dummies
#undef PHASE
#undef STG

  // ---- epilogue: out[m][n] = (acc + qbias[n]) * dscale[n] ----
  const int col = lane & 15;
  const int rb  = (lane >> 4) * 4;
  const int gm0 = tm * BM + wr * 128;
  const int gn0 = tn * BN + wc * 64;
#pragma unroll
  for (int ni = 0; ni < 4; ++ni) {
    int gn = gn0 + ni * 16 + col;
    float ds = dscale[gn];
    int qb = qbias[gn];
#pragma unroll
    for (int mi = 0; mi < 8; ++mi) {
      int gm = gm0 + mi * 16 + rb;
#pragma unroll
      for (int j = 0; j < 4; ++j)
        out[(size_t)(gm + j) * N_DIM + gn] = (float)(acc[mi][ni][j] + qb) * ds;
    }
  }
}

extern "C" void kernel_launch(void* const* d_in, const int* in_sizes, int n_in,
                              void* d_out, int out_size, void* d_ws, size_t ws_size,
                              hipStream_t stream) {
  const float* x      = (const float*)d_in[0];
  const int*   w      = (const int*)d_in[1];
  const float* dscale = (const float*)d_in[2];
  const float* iscale = (const float*)d_in[3];
  const int*   ioff   = (const int*)d_in[4];
  const int*   qbias  = (const int*)d_in[5];
  float* out = (float*)d_out;

  const size_t xq_bytes = (size_t)M_DIM * K_DIM;        // 16 MB
  const size_t wq_bytes = (size_t)N_DIM * K_DIM;        // 45 MB
  if (ws_size < xq_bytes + wq_bytes) return;

  signed char* xq = (signed char*)d_ws;
  signed char* wq = (signed char*)d_ws + xq_bytes;

  quant_x_kernel<<<2048, 256, 0, stream>>>(x, iscale, ioff, xq, M_DIM * K_DIM / 16);
  pack_w_kernel<<<2048, 256, 0, stream>>>(w, wq, N_DIM * K_DIM / 16);
  gemm_i8_kernel<<<NTM * NTN, 512, 0, stream>>>(xq, wq, qbias, dscale, out);
}

// Round 5
// 284.454 us; speedup vs baseline: 1.2368x; 1.0088x over previous
//
#include <hip/hip_runtime.h>
#include <cstdint>
#include <cstddef>

#define M_DIM 4096
#define K_DIM 4096
#define N_DIM 11008
#define BM 256
#define BN 256
#define BKB 128                       /* K bytes per K-tile (2 MFMA k-slices) */
#define NT (K_DIM / BKB)              /* 32 K-tiles */
#define NITER (NT / 2)                /* 16 iterations, 2 K-tiles each */
#define NTM (M_DIM / BM)              /* 16 */
#define NTN (N_DIM / BN)              /* 43 */
#define SLOT_BYTES 65536              /* per K-tile: A 32KB + B 32KB */
#define B_OFF 32768

typedef int   int4v   __attribute__((ext_vector_type(4)));
typedef float float4v __attribute__((ext_vector_type(4)));

__device__ __forceinline__ void gload_lds16(const void* g, void* l) {
  __builtin_amdgcn_global_load_lds(
      (const __attribute__((address_space(1))) unsigned int*)g,
      (__attribute__((address_space(3))) unsigned int*)l, 16, 0, 0);
}

// ---------------- x quantization: fp32 -> int8 ----------------
__global__ void quant_x_kernel(const float* __restrict__ x,
                               const float* __restrict__ scale_p,
                               const int* __restrict__ off_p,
                               signed char* __restrict__ xq, int total16) {
  const float inv = 1.0f / scale_p[0];
  const float off = (float)off_p[0];
  int tid = blockIdx.x * blockDim.x + threadIdx.x;
  int stride = gridDim.x * blockDim.x;
  const float4v* x4 = (const float4v*)x;
  int4v* out4 = (int4v*)xq;
  for (int i = tid; i < total16; i += stride) {
    int4v o;
#pragma unroll
    for (int j = 0; j < 4; ++j) {
      float4v v = x4[(size_t)i * 4 + j];
      int r = 0;
#pragma unroll
      for (int e = 0; e < 4; ++e) {
        float q = rintf(v[e] * inv) + off;     // round-half-even, matches jnp.round
        q = fminf(fmaxf(q, -128.0f), 127.0f);
        int qi = (int)q;
        r |= (qi & 0xff) << (8 * e);
      }
      o[j] = r;
    }
    out4[i] = o;
  }
}

// ---------------- weight pack: int32 carrier -> int8 ----------------
__global__ void pack_w_kernel(const int* __restrict__ w,
                              signed char* __restrict__ wq, int total16) {
  int tid = blockIdx.x * blockDim.x + threadIdx.x;
  int stride = gridDim.x * blockDim.x;
  const int4v* w4 = (const int4v*)w;
  int4v* out4 = (int4v*)wq;
  for (int i = tid; i < total16; i += stride) {
    int4v o;
#pragma unroll
    for (int j = 0; j < 4; ++j) {
      int4v v = w4[(size_t)i * 4 + j];
      o[j] = (v[0] & 0xff) | ((v[1] & 0xff) << 8) |
             ((v[2] & 0xff) << 16) | ((v[3] & 0xff) << 24);
    }
    out4[i] = o;
  }
}

// -------- int8 GEMM: 256x256, 8 waves, 8-phase, read-pipelined registers --------
// A: xq [M][K] int8, B: wq [N][K] int8 (B^T), out fp32 [M][N]
// LDS fragment-packed (0 conflicts): A frag(m,ks) at (2m+ks)*1024, B at
// B_OFF+(2n+ks)*1024; lane l's 16B at frag*1024+l*16 = [16*fr+(l&15)][(l>>4)*16..].
// Slot s = kt&1 at s*64KB.  Chunk c staged at phase (k,c) = chunk c of tile k+2.
// Read pipeline: phase (k,Q) issues the ds_reads for phase Q+1 into the
// alternate register buffer (afr parity Q&1, bfr parity tile&1), so the
// post-barrier wait is a COUNTED lgkmcnt (drains only reads issued a full
// phase earlier).  Reads/phase = {4,4,8,8}.  vmcnt(4) once per tile (Q1 end)
// guarantees tile k+1 fully in LDS before its B-reads at Q2.
__global__ __launch_bounds__(512, 2) void gemm_i8_kernel(
    const signed char* __restrict__ A,
    const signed char* __restrict__ B,
    const int* __restrict__ qbias,
    const float* __restrict__ dscale,
    float* __restrict__ out) {
  __shared__ __attribute__((aligned(16))) signed char lds[2 * SLOT_BYTES];  // 128 KB

  const int tid  = threadIdx.x;
  const int lane = tid & 63;
  const int wv   = tid >> 6;   // 0..7
  const int wr   = wv >> 2;    // 0..1  (M half: 128 rows)
  const int wc   = wv & 3;     // 0..3  (N quarter: 64 cols)

  // XCD swizzle: 688 blocks, 86/XCD; per XCD: 2 tm-rows x 43 tn, tn-fastest.
  int bid = blockIdx.x;
  int swz = (bid & 7) * 86 + (bid >> 3);
  int tm = swz / NTN;
  int tn = swz % NTN;

  // ---- staging assignment: wave wv stages rows ro+2c (c=chunk), k-slice sks ----
  const int sks = wv & 1;
  const int r2  = wv >> 1;
  const int ro  = (r2 & 1) | ((r2 & 2) << 2);   // 0,1,8,9

  const signed char* pA = A + (size_t)(tm * BM + ro * 16 + (lane & 15)) * K_DIM
                            + sks * 64 + (lane >> 4) * 16;
  const signed char* pB = B + (size_t)(tn * BN + ro * 16 + (lane & 15)) * K_DIM
                            + sks * 64 + (lane >> 4) * 16;
  const int ldsA0 = (ro * 2 + sks) * 1024;          // + c*4096 + slot*64K
  const int ldsB0 = B_OFF + (ro * 2 + sks) * 1024;

#define STG(ktS, c) do {                                                      \
    int ktw_ = (ktS) & (NT - 1);                                              \
    int sl_  = (ktw_ & 1) * SLOT_BYTES;                                       \
    gload_lds16(pA + (size_t)(c) * 32 * K_DIM + (size_t)ktw_ * BKB,           \
                lds + sl_ + ldsA0 + (c) * 4096);                              \
    gload_lds16(pB + (size_t)(c) * 32 * K_DIM + (size_t)ktw_ * BKB,           \
                lds + sl_ + ldsB0 + (c) * 4096); } while (0)

  // ---- ds_read bases (fragment-packed: base + lane*16, conflict-free) ----
  const int rdA0 = (wr * 8) * 2048 + lane * 16;          // + (2Q+d)*2048 + ks*1024
  const int rdB0 = B_OFF + (wc * 4) * 2048 + lane * 16;  // + ni*2048 + ks*1024

#define RD_A(dst, SB, QQ) do {                                                \
    _Pragma("unroll") for (int d = 0; d < 2; ++d)                             \
      _Pragma("unroll") for (int ks = 0; ks < 2; ++ks)                        \
        dst[d][ks] = *(const int4v*)(lds + (SB) + rdA0 + (2*(QQ)+d)*2048 + ks*1024); \
  } while (0)
#define RD_B2(dst, SB, NI0) do {                                              \
    _Pragma("unroll") for (int ii = 0; ii < 2; ++ii)                          \
      _Pragma("unroll") for (int ks = 0; ks < 2; ++ks)                        \
        dst[(NI0)+ii][ks] = *(const int4v*)(lds + (SB) + rdB0 + ((NI0)+ii)*2048 + ks*1024); \
  } while (0)
#define MFMA_Q(af, bf, QQ) do {                                               \
    __builtin_amdgcn_s_setprio(1);                                            \
    _Pragma("unroll") for (int d = 0; d < 2; ++d)                             \
      _Pragma("unroll") for (int ni = 0; ni < 4; ++ni)                        \
        _Pragma("unroll") for (int ks = 0; ks < 2; ++ks)                      \
          acc[2*(QQ)+d][ni] = __builtin_amdgcn_mfma_i32_16x16x64_i8(          \
              af[d][ks], bf[ni][ks], acc[2*(QQ)+d][ni], 0, 0, 0);             \
    __builtin_amdgcn_s_setprio(0);                                            \
  } while (0)
#define WAIT_LGKM(n) do {                                                     \
    asm volatile("s_waitcnt lgkmcnt(" #n ")" ::: "memory");                   \
    __builtin_amdgcn_sched_barrier(0);                                        \
  } while (0)

  int4v acc[8][4];
#pragma unroll
  for (int i = 0; i < 8; ++i)
#pragma unroll
    for (int j = 0; j < 4; ++j) acc[i][j] = (int4v){0, 0, 0, 0};

  int4v afr0[2][2], afr1[2][2], bfr0[4][2], bfr1[4][2];

  // ---- prologue ----
#pragma unroll
  for (int c = 0; c < 4; ++c) STG(0, c);
#pragma unroll
  for (int c = 0; c < 4; ++c) STG(1, c);
  asm volatile("s_waitcnt vmcnt(8)" ::: "memory");   // tile 0 landed
  __builtin_amdgcn_s_barrier();
  RD_A(afr0, 0, 0);                                  // A(0, Q0)
  RD_B2(bfr0, 0, 0);
  RD_B2(bfr0, 0, 2);                                 // B(0) complete
  asm volatile("s_waitcnt lgkmcnt(0)" ::: "memory");
  __builtin_amdgcn_sched_barrier(0);
  __builtin_amdgcn_s_barrier();

  // One K-tile = 4 phases.  S = slot const, AFC/AFN alternate per phase,
  // BFC = this tile's B regs, BFN = next tile's.  KST = tile k+2 (staged).
#define TILE4(S, BFC, BFN, KST) do {                                          \
    const int SB_  = (S) * SLOT_BYTES;                                        \
    const int SBn_ = (1 - (S)) * SLOT_BYTES;                                  \
    /* Q0 */                                                                  \
    RD_A(afr1, SB_, 1);                                                       \
    STG((KST), 0);                                                            \
    __builtin_amdgcn_s_barrier();                                             \
    WAIT_LGKM(4);                                                             \
    MFMA_Q(afr0, BFC, 0);                                                     \
    /* Q1 */                                                                  \
    RD_A(afr0, SB_, 2);                                                       \
    STG((KST), 1);                                                            \
    asm volatile("s_waitcnt vmcnt(4)" ::: "memory");  /* tile k+1 landed */   \
    __builtin_amdgcn_s_barrier();                                             \
    WAIT_LGKM(4);                                                             \
    MFMA_Q(afr1, BFC, 1);                                                     \
    /* Q2 */                                                                  \
    RD_A(afr1, SB_, 3);                                                       \
    RD_B2(BFN, SBn_, 0);                                                      \
    STG((KST), 2);                                                            \
    __builtin_amdgcn_s_barrier();                                             \
    WAIT_LGKM(8);                                                             \
    MFMA_Q(afr0, BFC, 2);                                                     \
    /* Q3 */                                                                  \
    RD_A(afr0, SBn_, 0);                                                      \
    RD_B2(BFN, SBn_, 2);                                                      \
    STG((KST), 3);                                                            \
    __builtin_amdgcn_s_barrier();                                             \
    WAIT_LGKM(8);                                                             \
    MFMA_Q(afr1, BFC, 3);                                                     \
  } while (0)

  for (int t = 0; t < NITER; ++t) {
    const int k0 = 2 * t;
    TILE4(0, bfr0, bfr1, k0 + 2);   // even tile, slot 0
    TILE4(1, bfr1, bfr0, k0 + 3);   // odd tile, slot 1
  }
  asm volatile("s_waitcnt vmcnt(0) lgkmcnt(0)" ::: "memory");  // drain tail dummies
#undef TILE4
#undef WAIT_LGKM
#undef MFMA_Q
#undef RD_B2
#undef RD_A
#undef STG

  // ---- epilogue: out[m][n] = (acc + qbias[n]) * dscale[n] ----
  const int col = lane & 15;
  const int rb  = (lane >> 4) * 4;
  const int gm0 = tm * BM + wr * 128;
  const int gn0 = tn * BN + wc * 64;
#pragma unroll
  for (int ni = 0; ni < 4; ++ni) {
    int gn = gn0 + ni * 16 + col;
    float ds = dscale[gn];
    int qb = qbias[gn];
#pragma unroll
    for (int mi = 0; mi < 8; ++mi) {
      int gm = gm0 + mi * 16 + rb;
#pragma unroll
      for (int j = 0; j < 4; ++j)
        out[(size_t)(gm + j) * N_DIM + gn] = (float)(acc[mi][ni][j] + qb) * ds;
    }
  }
}

extern "C" void kernel_launch(void* const* d_in, const int* in_sizes, int n_in,
                              void* d_out, int out_size, void* d_ws, size_t ws_size,
                              hipStream_t stream) {
  const float* x      = (const float*)d_in[0];
  const int*   w      = (const int*)d_in[1];
  const float* dscale = (const float*)d_in[2];
  const float* iscale = (const float*)d_in[3];
  const int*   ioff   = (const int*)d_in[4];
  const int*   qbias  = (const int*)d_in[5];
  float* out = (float*)d_out;

  const size_t xq_bytes = (size_t)M_DIM * K_DIM;        // 16 MB
  const size_t wq_bytes = (size_t)N_DIM * K_DIM;        // 45 MB
  if (ws_size < xq_bytes + wq_bytes) return;

  signed char* xq = (signed char*)d_ws;
  signed char* wq = (signed char*)d_ws + xq_bytes;

  quant_x_kernel<<<2048, 256, 0, stream>>>(x, iscale, ioff, xq, M_DIM * K_DIM / 16);
  pack_w_kernel<<<2048, 256, 0, stream>>>(w, wq, N_DIM * K_DIM / 16);
  gemm_i8_kernel<<<NTM * NTN, 512, 0, stream>>>(xq, wq, qbias, dscale, out);
}